// Round 7
// baseline (138.300 us; speedup 1.0000x reference)
//
#include <hip/hip_runtime.h>
#include <stdint.h>

typedef unsigned char      u8;
typedef unsigned int       u32;

#define N_ROWS 8192
#define N_HALF 4096
#define DDIM   1024
#define BM     256            // block tile (256x256)
#define BKB    128            // K-bytes staged per iter (=128 fp8 elems)
#define NKT    (DDIM / BKB)   // 8
#define NBLK_PREP 1024
#define NT256  (32 * 33 / 2)  // 528 triangular 256x256 tiles
#define SLOT   65536          // one kt buffer: 512 rows x 128 B

typedef int   i32x4 __attribute__((ext_vector_type(4)));
typedef int   i32x8 __attribute__((ext_vector_type(8)));
typedef float f32x4 __attribute__((ext_vector_type(4)));

// ---- workspace (~8.04 MB): every byte written before read; zero atomics ----
#define OFF_X8   ((size_t)0)
#define SZ_X8    ((size_t)N_ROWS * DDIM)          // 8 MB fp8 [source;target]
#define OFF_SQ   (SZ_X8)                          // 8192 f32 row sq-norms (fp8-consistent)
#define OFF_SQP  (OFF_SQ + (size_t)N_ROWS * 4)    // sqpart[1024]
#define OFF_TS   (OFF_SQP + (size_t)NBLK_PREP * 4)// tilesum[528]
#define WS_NEED  (OFF_TS + (size_t)NT256 * 4)

#define AS1(p) ((__attribute__((address_space(1))) void*)(p))
#define AS3(p) ((__attribute__((address_space(3))) void*)(p))

// ---------------------------------------------------------------------------
// Kernel A: fp32 -> fp8(e4m3, RNE HW cvt) copy, row sq-norms from DEQUANTIZED
// fp8 values (keeps diagonal L2 ~ 0), per-block sum-of-sq partial.
// 1024 blocks x 256 threads, 2 rows/wave. (R0-validated, untouched)
// ---------------------------------------------------------------------------
__global__ __launch_bounds__(256) void prep_kernel(const float* __restrict__ src,
                                                   const float* __restrict__ tgt,
                                                   u32* __restrict__ xb,
                                                   float* __restrict__ sqv,
                                                   float* __restrict__ sqpart) {
  __shared__ float wsq[4];
  const int tid  = threadIdx.x;
  const int lane = tid & 63;
  const int wave = tid >> 6;
  const int gw   = blockIdx.x * 4 + wave;     // 0..4095
  float wsum = 0.f;                           // valid on lane 0
#pragma unroll
  for (int rr = 0; rr < 2; ++rr) {
    const int r = gw * 2 + rr;                // 0..8191
    const float* rowp = (r < N_HALF) ? (src + (size_t)r * DDIM)
                                     : (tgt + (size_t)(r - N_HALF) * DDIM);
    float s = 0.f;
#pragma unroll
    for (int chn = 0; chn < 4; ++chn) {
      const int c0 = chn * 256 + lane * 4;
      float4 v = *(const float4*)(rowp + c0);
      int p = __builtin_amdgcn_cvt_pk_fp8_f32(v.x, v.y, 0, false);
      p     = __builtin_amdgcn_cvt_pk_fp8_f32(v.z, v.w, p, true);
      xb[(size_t)r * 256 + (c0 >> 2)] = (u32)p;
      float fx = __builtin_amdgcn_cvt_f32_fp8(p, 0);
      float fy = __builtin_amdgcn_cvt_f32_fp8(p, 1);
      float fz = __builtin_amdgcn_cvt_f32_fp8(p, 2);
      float fw = __builtin_amdgcn_cvt_f32_fp8(p, 3);
      s = fmaf(fx, fx, s); s = fmaf(fy, fy, s);
      s = fmaf(fz, fz, s); s = fmaf(fw, fw, s);
    }
#pragma unroll
    for (int off = 32; off; off >>= 1) s += __shfl_down(s, off);
    if (lane == 0) { sqv[r] = s; wsum += s; }
  }
  if (lane == 0) wsq[wave] = wsum;
  __syncthreads();
  if (tid == 0) sqpart[blockIdx.x] = (wsq[0] + wsq[1]) + (wsq[2] + wsq[3]);
}

// ---------------------------------------------------------------------------
// Kernel B: fused Gram + MMD, MX-fp8. R7: 256x256 tiles + R6's counted-vmcnt
// dbuf schedule. Six-round model: all adequately-pipelined variants converge
// on ~9-10 TB/s of logical staged traffic (xb 8MB > 4MB/XCD L2 -> LLC-
// dominated service). R0 = 532 MB / 9.8 TB/s = 54us. Only lever: traffic
// volume = (BM+BN)*BKB/(BM*BN) per output -> 256^2 halves it (270 MB).
// R5's 512-thr attempt failed on full-drain barriers (4.7 TB/s regime);
// R6 proved counted vmcnt sustains the pipe at low residency. Here:
// 528 blocks, 8 waves, dbuf 2x64KB -> 1 block/CU; in-flight ~128KB/CU >>
// BW*latency (~30KB), so 8 waves suffice for the BW ceiling.
// Per-wave maps are R0-VERBATIM (8-row staging groups, tau chunk map, frag
// offsets); wave tile 64x128 -> acc[4][8] in AGPRs. Waves 0-3 stage A rows,
// 4-7 stage B rows (exactly 8 global_load_lds/wave/round -> vmcnt(8)
// literal, R6-audited). Diagonal 256-tiles contain both mirror copies of
// their off-diag 128-subtiles -> scalar per-block weight (1 diag, 2 off).
// MFMA: mfma_scale_f32_16x16x128_f8f6f4, unit E8M0 scales (exact fp8 GEMM).
// C/D: col = lane&15, row = q*4 + v.
// ---------------------------------------------------------------------------
__global__ __launch_bounds__(512) void mmd_kernel(const u8* __restrict__ xb,
                                                  const float* __restrict__ sqv,
                                                  const float* __restrict__ sqpart,
                                                  float* __restrict__ tilesum) {
  __shared__ __align__(16) u8 smem[2 * SLOT];    // 128 KB: [cur][512 rows][128B]
  __shared__ float wred[8];
  __shared__ float bwsh;

  // triangular decode: block t -> (BY, BX), BY >= BX, BY in 0..31
  const int t = (int)blockIdx.x;
  int BY = (int)((sqrtf(8.f * (float)t + 1.f) - 1.f) * 0.5f);
  while ((BY + 1) * (BY + 2) / 2 <= t) ++BY;
  while (BY * (BY + 1) / 2 > t) --BY;
  const int BX = t - BY * (BY + 1) / 2;

  const int tid  = threadIdx.x;
  const int lane = tid & 63;
  const int wave = tid >> 6;         // 0..7
  const int m16  = lane & 15;        // MFMA m/n index
  const int q    = lane >> 4;        // quad: k-block owner
  const int m8   = (lane >> 3) & 1;  // row's region half
  const int w7   = lane & 7;
  const int wrow = (wave >> 1) * 64; // 0,64,128,192 (4 row groups)
  const int wcol = (wave & 1) * 128; // 0,128        (2 col groups)
  const int rowbase = BY * BM;
  const int colbase = BX * BM;

  // ---- bandwidth from sqpart (wave 0, before K-loop; R0-validated spot) ----
  if (tid < 64) {
    float S = 0.f;
#pragma unroll
    for (int i = 0; i < 16; ++i) S += sqpart[tid * 16 + i];
#pragma unroll
    for (int off = 32; off; off >>= 1) S += __shfl_down(S, off);
    if (tid == 0) {
      double sumL2 = 2.0 * 8192.0 * (double)S;   // ||colsum||^2 term ~1e-4 rel, dropped
      double bwv = sumL2 / (8192.0 * 8192.0 - 8192.0) / 4.0;
      bwsh = (float)(-0.0625 * 1.4426950408889634 / bwv);  // -(1/16)/bw * log2e
    }
  }

  f32x4 acc[4][8];
#pragma unroll
  for (int mi = 0; mi < 4; ++mi)
#pragma unroll
    for (int ni = 0; ni < 8; ++ni) acc[mi][ni] = f32x4{0.f, 0.f, 0.f, 0.f};

  // staging (R0-verbatim maps): LDS row R = wave*64 + i*8 + rr, i=0..7.
  // waves 0-3 cover R 0..255 (A panel), waves 4-7 cover R 256..511 (B panel)
  // -> single global base per wave, linear in i. Lane writes slot w7 of row
  // rr -> fetch global chunk tau^-1(w7^rr): uu=w7^rr; ch=(uu&3)*2+(uu>>2).
  const int rr = lane >> 3;
  const int uu = w7 ^ rr;
  const int ch = ((uu & 3) << 1) | (uu >> 2);
  const int srow0 = (wave < 4) ? (rowbase + wave * 64 + rr)
                               : (colbase + (wave - 4) * 64 + rr);
  const u8* gbase = xb + (size_t)srow0 * DDIM + ch * 16;

  // frag read offsets (R0-verbatim formulas): A region at LDS bytes 0..32767,
  // B region at 32768..65535 within each slot.
  const int sl1  = q ^ w7;
  const int o_lo = sl1 * 16;
  const int o_hi = (sl1 ^ 4) * 16;
  const int aoff = ((wrow >> 3) + m8) * 1024 + w7 * 128;           // + mi*2048
  const int boff = 32768 + ((wcol >> 3) + m8) * 1024 + w7 * 128;   // + ni*2048

#define STAGE(curbuf, ktc)                                                       \
  _Pragma("unroll")                                                              \
  for (int i = 0; i < 8; ++i)                                                    \
    __builtin_amdgcn_global_load_lds(AS1(gbase + (size_t)i * 8 * DDIM + (ktc) * BKB), \
        AS3(smem + (size_t)(curbuf) * SLOT + wave * 8192 + i * 1024), 16, 0, 0);

#define SBAR()   asm volatile("s_barrier" ::: "memory")
#define VMW(n)   asm volatile("s_waitcnt vmcnt(" #n ")" ::: "memory")

  // zero per-wave outstanding-vmem count (wave0's sqpart loads) so counted
  // waits are exact
  VMW(0);

  // prologue: kt0 -> buf0, kt1 -> buf1; wait kt0 (8 newest = kt1 in flight)
  STAGE(0, 0)
  STAGE(1, 1)
  VMW(8);
  SBAR();

  int cur = 0;
#pragma unroll 1
  for (int kt = 0; kt < NKT; ++kt) {
    // ---- compute buffer cur ----
    const u8* sa = smem + (size_t)cur * SLOT;
    i32x8 af[4];
#pragma unroll
    for (int mi = 0; mi < 4; ++mi) {
      const u8* pa = sa + aoff + mi * 2048;
      i32x4 lo = *(const i32x4*)(pa + o_lo);
      i32x4 hi = *(const i32x4*)(pa + o_hi);
      af[mi] = __builtin_shufflevector(lo, hi, 0, 1, 2, 3, 4, 5, 6, 7);
    }
#pragma unroll
    for (int ni = 0; ni < 8; ++ni) {
      const u8* pb = sa + boff + ni * 2048;
      i32x4 lo = *(const i32x4*)(pb + o_lo);
      i32x4 hi = *(const i32x4*)(pb + o_hi);
      i32x8 bfv = __builtin_shufflevector(lo, hi, 0, 1, 2, 3, 4, 5, 6, 7);
#pragma unroll
      for (int mi = 0; mi < 4; ++mi)
        acc[mi][ni] = __builtin_amdgcn_mfma_scale_f32_16x16x128_f8f6f4(
            af[mi], bfv, acc[mi][ni],
            0, 0,                     // cbsz=fp8(e4m3), blgp=fp8(e4m3)
            0, 0x7F7F7F7F,            // opsel_a, scale_a = E8M0 unit (2^0)
            0, 0x7F7F7F7F);           // opsel_b, scale_b
    }
    if (kt == NKT - 1) break;
    SBAR();                          // WAR: all waves done reading buf[cur]
    if (kt < NKT - 2) {
      STAGE(cur, kt + 2)             // 16 outstanding
      VMW(8);                        // kt+1's loads (other buf) done
    } else {
      VMW(0);                        // kt==6: drain kt7's loads
    }
    SBAR();                          // publish next buffer
    cur ^= 1;
  }
#undef STAGE
#undef SBAR
#undef VMW

  // ---- fused epilogue (C/D: col = lane&15, row = q*4 + v) ----
  const float nib = bwsh;
  float sqc[8];
#pragma unroll
  for (int ni = 0; ni < 8; ++ni) sqc[ni] = sqv[colbase + wcol + ni * 16 + m16];

  float tsum = 0.f;
#pragma unroll
  for (int mi = 0; mi < 4; ++mi) {
#pragma unroll
    for (int v = 0; v < 4; ++v) {
      const float sqr = sqv[rowbase + wrow + mi * 16 + q * 4 + v];
#pragma unroll
      for (int ni = 0; ni < 8; ++ni) {
        const float L2 = fmaf(-2.f, acc[mi][ni][v], sqr + sqc[ni]);
        const float e16 = exp2f(L2 * nib);      // log2e pre-folded into nib
        const float e8 = e16 * e16;
        const float e4 = e8 * e8;
        const float e2 = e4 * e4;
        const float e1 = e2 * e2;
        tsum += (e16 + e8) + (e4 + e2) + e1;
      }
    }
  }
#pragma unroll
  for (int off = 32; off; off >>= 1) tsum += __shfl_down(tsum, off);
  if (lane == 0) wred[wave] = tsum;
  __syncthreads();
  if (tid == 0) {
    float bs = 0.f;
#pragma unroll
    for (int w = 0; w < 8; ++w) bs += wred[w];
    const float sgn = ((BY < 16) == (BX < 16)) ? 1.f : -1.f;
    const float wgt = (BX == BY) ? 1.f : 2.f;
    tilesum[t] = sgn * wgt * bs;
  }
}

// ---------------------------------------------------------------------------
// Kernel C: deterministic final reduce (fixed order, double) -> mean / n^2.
// Separate dispatch (R4-validated: no cross-block ticket).
// ---------------------------------------------------------------------------
__global__ void fin_kernel(const float* __restrict__ tilesum, float* __restrict__ out) {
  __shared__ double red[4];
  const int t = threadIdx.x, lane = t & 63, wave = t >> 6;
  double s = 0.0;
  for (int i = t; i < NT256; i += 256) s += (double)tilesum[i];
#pragma unroll
  for (int off = 32; off; off >>= 1) s += __shfl_down(s, off);
  if (lane == 0) red[wave] = s;
  __syncthreads();
  if (t == 0) {
    double total = red[0] + red[1] + red[2] + red[3];
    out[0] = (float)(total / 16777216.0);   // mean over n^2 = 4096^2
  }
}

extern "C" void kernel_launch(void* const* d_in, const int* in_sizes, int n_in,
                              void* d_out, int out_size, void* d_ws, size_t ws_size,
                              hipStream_t stream) {
  if (ws_size < WS_NEED) return;  // ~8.04 MB scratch
  const float* src = (const float*)d_in[0];
  const float* tgt = (const float*)d_in[1];
  char* ws = (char*)d_ws;
  u32*   xb  = (u32*)(ws + OFF_X8);
  float* sqv = (float*)(ws + OFF_SQ);
  float* sqp = (float*)(ws + OFF_SQP);
  float* ts  = (float*)(ws + OFF_TS);

  prep_kernel<<<NBLK_PREP, 256, 0, stream>>>(src, tgt, xb, sqv, sqp);
  mmd_kernel<<<NT256, 512, 0, stream>>>((const u8*)xb, sqv, sqp, ts);
  fin_kernel<<<1, 256, 0, stream>>>(ts, (float*)d_out);
}

// Round 8
// 125.730 us; speedup vs baseline: 1.1000x; 1.1000x over previous
//
#include <hip/hip_runtime.h>
#include <stdint.h>

typedef unsigned char      u8;
typedef unsigned int       u32;

#define N_ROWS 8192
#define N_HALF 4096
#define DDIM   1024
#define TILE   128
#define NKT    8              // k-chunks of 128
#define NBLK_PREP 1024
#define NTILES (64 * 65 / 2)  // 2080 triangular 128x128 tiles
#define NXCD   8
#define TPX    (NTILES / NXCD)  // 260, exact -> bijective chunk swizzle

typedef int   i32x4 __attribute__((ext_vector_type(4)));
typedef int   i32x8 __attribute__((ext_vector_type(8)));
typedef float f32x4 __attribute__((ext_vector_type(4)));

// ---- workspace (~8.04 MB): every byte written before read; zero atomics ----
// xb layout (FRAGMENT-MAJOR, new in R8): for row-group rg = r>>4 and k-chunk
// kc = k>>7, a 2 KB block at (rg*8 + kc)*2048 stores bytes such that MFMA
// lane l reads its 32-byte A/B fragment slice as TWO DENSE dwordx4:
//   block[h*1024 + l*16 + j] = X8[rg*16 + (l&15)][kc*128 + (l>>4)*32 + h*16 + j]
// This is exactly the verified R0 fragment map (lane l <-> row l&15,
// k-window 32*(l>>4), lo regs k+0..15, hi regs k+16..31), materialized in
// global memory so the K-loop needs NO LDS and NO barriers.
#define OFF_X8   ((size_t)0)
#define SZ_X8    ((size_t)N_ROWS * DDIM)          // 8 MB fp8 fragment-major
#define OFF_SQ   (SZ_X8)                          // 8192 f32 row sq-norms (fp8-consistent)
#define OFF_SQP  (OFF_SQ + (size_t)N_ROWS * 4)    // sqpart[1024]
#define OFF_TS   (OFF_SQP + (size_t)NBLK_PREP * 4)// tilesum[2080]
#define WS_NEED  (OFF_TS + (size_t)NTILES * 4)

// ---------------------------------------------------------------------------
// Kernel A: fp32 -> fp8(e4m3, RNE HW cvt), row sq-norms from DEQUANTIZED fp8
// (keeps diagonal L2 ~ 0), per-block sum-of-sq partial. Same compute as R0;
// only the xb write INDEX changed (fragment-major permutation above).
// Writes land as 8x32B segments per wave-chunk: slightly less dense, but
// prep is bound by the 64 MB fp32 READ, not the 8 MB write.
// ---------------------------------------------------------------------------
__global__ __launch_bounds__(256) void prep_kernel(const float* __restrict__ src,
                                                   const float* __restrict__ tgt,
                                                   u32* __restrict__ xb,
                                                   float* __restrict__ sqv,
                                                   float* __restrict__ sqpart) {
  __shared__ float wsq[4];
  const int tid  = threadIdx.x;
  const int lane = tid & 63;
  const int wave = tid >> 6;
  const int gw   = blockIdx.x * 4 + wave;     // 0..4095
  float wsum = 0.f;                           // valid on lane 0
#pragma unroll
  for (int rr = 0; rr < 2; ++rr) {
    const int r = gw * 2 + rr;                // 0..8191
    const float* rowp = (r < N_HALF) ? (src + (size_t)r * DDIM)
                                     : (tgt + (size_t)(r - N_HALF) * DDIM);
    const int rg  = r >> 4;
    const int r16 = r & 15;
    float s = 0.f;
#pragma unroll
    for (int chn = 0; chn < 4; ++chn) {
      const int k0 = chn * 256 + lane * 4;    // 4 consecutive k
      float4 v = *(const float4*)(rowp + k0);
      int p = __builtin_amdgcn_cvt_pk_fp8_f32(v.x, v.y, 0, false);
      p     = __builtin_amdgcn_cvt_pk_fp8_f32(v.z, v.w, p, true);
      // fragment-major index (u32 units): block (rg*8+kc) of 512 u32;
      // within: h*256 + l'*4 + (k0&15)/4, l' = r16 + 16*((k0&127)>>5)
      const int kc = k0 >> 7;
      const int kk = k0 & 127;
      const int lp = r16 + ((kk >> 5) << 4);
      const int h  = (kk >> 4) & 1;
      xb[(size_t)(rg * 8 + kc) * 512 + h * 256 + lp * 4 + ((k0 & 15) >> 2)] = (u32)p;
      float fx = __builtin_amdgcn_cvt_f32_fp8(p, 0);
      float fy = __builtin_amdgcn_cvt_f32_fp8(p, 1);
      float fz = __builtin_amdgcn_cvt_f32_fp8(p, 2);
      float fw = __builtin_amdgcn_cvt_f32_fp8(p, 3);
      s = fmaf(fx, fx, s); s = fmaf(fy, fy, s);
      s = fmaf(fz, fz, s); s = fmaf(fw, fw, s);
    }
#pragma unroll
    for (int off = 32; off; off >>= 1) s += __shfl_down(s, off);
    if (lane == 0) { sqv[r] = s; wsum += s; }
  }
  if (lane == 0) wsq[wave] = wsum;
  __syncthreads();
  if (tid == 0) sqpart[blockIdx.x] = (wsq[0] + wsq[1]) + (wsq[2] + wsq[3]);
}

// ---------------------------------------------------------------------------
// Kernel B: fused Gram + MMD, MX-fp8. R8: ZERO-LDS direct-fragment streaming.
// Eight-round model: every LDS-staged variant is capped by the per-CU
// global_load_lds port (~16 B/cy at 12 waves/CU, less at 8) and fat-acc
// tiles lose occupancy exactly as fast as they cut traffic. This kernel
// loads A/B fragments straight from the fragment-major xb into VGPRs as
// dense dwordx4 pairs (lane*16). No LDS staging, no K-loop barriers; the
// per-kt K-slice of ALL of xb is 1 MB -> fits every XCD L2, so loads are
// L2-hits on the vector path (34.5 TB/s aggregate), not the staging port.
// 1.06 GB logical / 34.5 TB/s ~= 31 us vs R0's 54. Latency hidden by 12
// waves/CU of pure TLP (independent waves, Guideline 1/m114).
// Wave tile 64x64, acc 64 regs, __launch_bounds__(256,3) targets 3 w/SIMD.
// XCD-chunked swizzle kept: panel-level L2 reuse (per-kt slice fits anyway).
// One barrier total (publish bwsh before epilogue).
// MFMA: mfma_scale_f32_16x16x128_f8f6f4, unit E8M0 scales (exact fp8 GEMM).
// C/D: col = lane&15, row = q*4 + v. Math identical to R0 -> same absmax.
// ---------------------------------------------------------------------------
__global__ __launch_bounds__(256, 3) void mmd_kernel(const u8* __restrict__ xb,
                                                     const float* __restrict__ sqv,
                                                     const float* __restrict__ sqpart,
                                                     float* __restrict__ tilesum) {
  __shared__ float wred[4];
  __shared__ float bwsh;

  // XCD-chunked swizzle: XCD (t0&7) gets contiguous tile range [x*260,(x+1)*260)
  const int t0 = (int)blockIdx.x;
  const int t  = (t0 & 7) * TPX + (t0 >> 3);

  // triangular decode: tile t -> (by, bx) with by >= bx
  int by = (int)((sqrtf(8.f * (float)t + 1.f) - 1.f) * 0.5f);
  while ((by + 1) * (by + 2) / 2 <= t) ++by;
  while (by * (by + 1) / 2 > t) --by;
  const int bx = t - by * (by + 1) / 2;

  const int tid  = threadIdx.x;
  const int lane = tid & 63;
  const int wave = tid >> 6;
  const int m16  = lane & 15;        // MFMA m/n index
  const int q    = lane >> 4;        // quad: k-block owner
  const int wrow = (wave >> 1) * 64; // wave's 64x64 quadrant
  const int wcol = (wave & 1) * 64;
  const int rowbase = by * TILE;
  const int colbase = bx * TILE;

  // ---- bandwidth from sqpart (wave 0; published by the single barrier) ----
  if (tid < 64) {
    float S = 0.f;
#pragma unroll
    for (int i = 0; i < 16; ++i) S += sqpart[tid * 16 + i];
#pragma unroll
    for (int off = 32; off; off >>= 1) S += __shfl_down(S, off);
    if (tid == 0) {
      double sumL2 = 2.0 * 8192.0 * (double)S;   // ||colsum||^2 term ~1e-4 rel, dropped
      double bwv = sumL2 / (8192.0 * 8192.0 - 8192.0) / 4.0;
      bwsh = (float)(-0.0625 * 1.4426950408889634 / bwv);  // -(1/16)/bw * log2e
    }
  }

  f32x4 acc[4][4];
#pragma unroll
  for (int mi = 0; mi < 4; ++mi)
#pragma unroll
    for (int ni = 0; ni < 4; ++ni) acc[mi][ni] = f32x4{0.f, 0.f, 0.f, 0.f};

  // fragment bases: rg runs of 8 k-chunks of 2 KB; +16384 per mi/ni (next rg)
  const u8* pA0 = xb + (size_t)(((rowbase + wrow) >> 4) * 8) * 2048 + lane * 16;
  const u8* pB0 = xb + (size_t)(((colbase + wcol) >> 4) * 8) * 2048 + lane * 16;

#pragma unroll 1
  for (int kt = 0; kt < NKT; ++kt) {
    const u8* pA = pA0 + kt * 2048;
    const u8* pB = pB0 + kt * 2048;
    i32x8 af[4], bf[4];
#pragma unroll
    for (int mi = 0; mi < 4; ++mi) {
      i32x4 lo = *(const i32x4*)(pA + mi * 16384);
      i32x4 hi = *(const i32x4*)(pA + mi * 16384 + 1024);
      af[mi] = __builtin_shufflevector(lo, hi, 0, 1, 2, 3, 4, 5, 6, 7);
    }
#pragma unroll
    for (int ni = 0; ni < 4; ++ni) {
      i32x4 lo = *(const i32x4*)(pB + ni * 16384);
      i32x4 hi = *(const i32x4*)(pB + ni * 16384 + 1024);
      bf[ni] = __builtin_shufflevector(lo, hi, 0, 1, 2, 3, 4, 5, 6, 7);
    }
#pragma unroll
    for (int mi = 0; mi < 4; ++mi)
#pragma unroll
      for (int ni = 0; ni < 4; ++ni)
        acc[mi][ni] = __builtin_amdgcn_mfma_scale_f32_16x16x128_f8f6f4(
            af[mi], bf[ni], acc[mi][ni],
            0, 0,                     // cbsz=fp8(e4m3), blgp=fp8(e4m3)
            0, 0x7F7F7F7F,            // opsel_a, scale_a = E8M0 unit (2^0)
            0, 0x7F7F7F7F);           // opsel_b, scale_b
  }

  __syncthreads();                   // publish bwsh (only barrier pre-epilogue)

  // ---- fused epilogue (C/D: col = lane&15, row = q*4 + v) ----
  const float nib = bwsh;
  float sqc[4];
#pragma unroll
  for (int ni = 0; ni < 4; ++ni) sqc[ni] = sqv[colbase + wcol + ni * 16 + m16];

  float tsum = 0.f;
#pragma unroll
  for (int mi = 0; mi < 4; ++mi) {
#pragma unroll
    for (int v = 0; v < 4; ++v) {
      const float sqr = sqv[rowbase + wrow + mi * 16 + q * 4 + v];
#pragma unroll
      for (int ni = 0; ni < 4; ++ni) {
        const float L2 = fmaf(-2.f, acc[mi][ni][v], sqr + sqc[ni]);
        const float e16 = exp2f(L2 * nib);      // log2e pre-folded into nib
        const float e8 = e16 * e16;
        const float e4 = e8 * e8;
        const float e2 = e4 * e4;
        const float e1 = e2 * e2;
        tsum += (e16 + e8) + (e4 + e2) + e1;
      }
    }
  }
#pragma unroll
  for (int off = 32; off; off >>= 1) tsum += __shfl_down(tsum, off);
  if (lane == 0) wred[wave] = tsum;
  __syncthreads();
  if (tid == 0) {
    const float bs = (wred[0] + wred[1]) + (wred[2] + wred[3]);
    const float sgn = ((by < 32) == (bx < 32)) ? 1.f : -1.f;
    const float wgt = (bx == by) ? 1.f : 2.f;
    tilesum[t] = sgn * wgt * bs;
  }
}

// ---------------------------------------------------------------------------
// Kernel C: deterministic final reduce (fixed order, double) -> mean / n^2.
// Separate dispatch (R4-validated: no cross-block ticket).
// ---------------------------------------------------------------------------
__global__ void fin_kernel(const float* __restrict__ tilesum, float* __restrict__ out) {
  __shared__ double red[4];
  const int t = threadIdx.x, lane = t & 63, wave = t >> 6;
  double s = 0.0;
  for (int i = t; i < NTILES; i += 256) s += (double)tilesum[i];
#pragma unroll
  for (int off = 32; off; off >>= 1) s += __shfl_down(s, off);
  if (lane == 0) red[wave] = s;
  __syncthreads();
  if (t == 0) {
    double total = red[0] + red[1] + red[2] + red[3];
    out[0] = (float)(total / 16777216.0);   // mean over n^2 = 4096^2
  }
}

extern "C" void kernel_launch(void* const* d_in, const int* in_sizes, int n_in,
                              void* d_out, int out_size, void* d_ws, size_t ws_size,
                              hipStream_t stream) {
  if (ws_size < WS_NEED) return;  // ~8.04 MB scratch
  const float* src = (const float*)d_in[0];
  const float* tgt = (const float*)d_in[1];
  char* ws = (char*)d_ws;
  u32*   xb  = (u32*)(ws + OFF_X8);
  float* sqv = (float*)(ws + OFF_SQ);
  float* sqp = (float*)(ws + OFF_SQP);
  float* ts  = (float*)(ws + OFF_TS);

  prep_kernel<<<NBLK_PREP, 256, 0, stream>>>(src, tgt, xb, sqv, sqp);
  mmd_kernel<<<NTILES, 256, 0, stream>>>((const u8*)xb, sqv, sqp, ts);
  fin_kernel<<<1, 256, 0, stream>>>(ts, (float*)d_out);
}